// Round 3
// baseline (230.933 us; speedup 1.0000x reference)
//
#include <hip/hip_runtime.h>
#include <math.h>

// Problem constants
#define BB 128
#define KK 32
#define JJ 1152
#define II 8
#define ZZ 16

#define JCB 32              // j's per block (hot kernels)
#define NJC (JJ / JCB)      // 36 chunks
#define JPW (JCB / 4)       // 8 j's per wave (4 waves/block)
#define BCB 64              // b's per block (one per lane)
#define NBC (BB / BCB)      // 2

// Workspace layout (floats): accumulators first (memset), xT after.
#define N_USUM (KK * ZZ * BB)   // [k][z][b]   65536
#define N_S    (JJ * BB)        // [j][b]     147456
#define N_SACC (KK * ZZ * BB)   // [k][z][b]   65536
#define N_ACC  (N_USUM + N_S + N_SACC)
#define N_XT   (JJ * BB * II)   // [j][b][i] 1179648

// ---- Transpose: x[b][j][i] -> xT[j][b][i] (float4 granularity) ----
extern "C" __global__ __launch_bounds__(256)
void kT(const float* __restrict__ x, float* __restrict__ xT) {
    int idx = blockIdx.x * 256 + threadIdx.x;       // float4 index in xT
    // xT float4 layout: [j][b][i4], i4 in {0,1}
    int j  = idx >> 8;            // / (BB*2)
    int r  = idx & 255;
    int b  = r >> 1;
    int i4 = r & 1;
    float4 v = ((const float4*)x)[((size_t)b * JJ + j) * 2 + i4];
    ((float4*)xT)[idx] = v;       // fully coalesced write
}

// Compute u[z] for one (b, j): W via wave-uniform (scalar) loads, x in regs.
__device__ __forceinline__ void compute_uz(const float* __restrict__ Wj,
                                           const float4 xa, const float4 xb4,
                                           float uz[ZZ]) {
#pragma unroll
    for (int z = 0; z < ZZ; ++z) uz[z] = 0.f;
    const float xi[II] = {xa.x, xa.y, xa.z, xa.w, xb4.x, xb4.y, xb4.z, xb4.w};
#pragma unroll
    for (int i = 0; i < II; ++i) {
        const float4* wp = (const float4*)(Wj + i * ZZ);   // uniform -> s_load
        float4 w0 = wp[0], w1 = wp[1], w2 = wp[2], w3 = wp[3];
        float xv = xi[i];
        uz[0]  = fmaf(xv, w0.x, uz[0]);  uz[1]  = fmaf(xv, w0.y, uz[1]);
        uz[2]  = fmaf(xv, w0.z, uz[2]);  uz[3]  = fmaf(xv, w0.w, uz[3]);
        uz[4]  = fmaf(xv, w1.x, uz[4]);  uz[5]  = fmaf(xv, w1.y, uz[5]);
        uz[6]  = fmaf(xv, w1.z, uz[6]);  uz[7]  = fmaf(xv, w1.w, uz[7]);
        uz[8]  = fmaf(xv, w2.x, uz[8]);  uz[9]  = fmaf(xv, w2.y, uz[9]);
        uz[10] = fmaf(xv, w2.z, uz[10]); uz[11] = fmaf(xv, w2.w, uz[11]);
        uz[12] = fmaf(xv, w3.x, uz[12]); uz[13] = fmaf(xv, w3.y, uz[13]);
        uz[14] = fmaf(xv, w3.z, uz[14]); uz[15] = fmaf(xv, w3.w, uz[15]);
    }
}

// ---- Pass A: usum[k][z][b] = sum_j u[b,k,j,z] ----
extern "C" __global__ __launch_bounds__(256)
void kA(const float* __restrict__ xT, const float* __restrict__ W,
        float* __restrict__ usum) {
    const int jcb = blockIdx.x * JCB;
    const int k   = blockIdx.y;
    const int bc  = blockIdx.z;
    const int t   = threadIdx.x;
    const int w   = __builtin_amdgcn_readfirstlane(t >> 6);
    const int lb  = t & 63;
    const int bg  = bc * BCB + lb;

    float acc[ZZ];
#pragma unroll
    for (int z = 0; z < ZZ; ++z) acc[z] = 0.f;

    const int j0 = jcb + w * JPW;
    const float* Wk = W + ((size_t)k * JJ + j0) * II * ZZ;
#pragma unroll
    for (int jl = 0; jl < JPW; ++jl) {
        const float4* xp = (const float4*)(xT + ((size_t)(j0 + jl) * BB + bg) * II);
        float4 xa = xp[0], xb4 = xp[1];          // coalesced 32B/lane
        float uz[ZZ];
        compute_uz(Wk + (size_t)jl * II * ZZ, xa, xb4, uz);
#pragma unroll
        for (int z = 0; z < ZZ; ++z) acc[z] += uz[z];
    }
#pragma unroll
    for (int z = 0; z < ZZ; ++z)
        unsafeAtomicAdd(&usum[(k * ZZ + z) * BB + bg], acc[z]);
}

// ---- Pass B: S[j][b] = sum_k exp( dot_z(u, usum) / 4 ) ----
extern "C" __global__ __launch_bounds__(256)
void kB(const float* __restrict__ xT, const float* __restrict__ W,
        const float* __restrict__ usum, float* __restrict__ S) {
    const int jcb = blockIdx.x * JCB;
    const int k   = blockIdx.y;
    const int bc  = blockIdx.z;
    const int t   = threadIdx.x;
    const int w   = __builtin_amdgcn_readfirstlane(t >> 6);
    const int lb  = t & 63;
    const int bg  = bc * BCB + lb;

    float us[ZZ];
#pragma unroll
    for (int z = 0; z < ZZ; ++z) us[z] = usum[(k * ZZ + z) * BB + bg];

    const int j0 = jcb + w * JPW;
    const float* Wk = W + ((size_t)k * JJ + j0) * II * ZZ;
#pragma unroll
    for (int jl = 0; jl < JPW; ++jl) {
        const float4* xp = (const float4*)(xT + ((size_t)(j0 + jl) * BB + bg) * II);
        float4 xa = xp[0], xb4 = xp[1];
        float uz[ZZ];
        compute_uz(Wk + (size_t)jl * II * ZZ, xa, xb4, uz);
        float dp = 0.f;
#pragma unroll
        for (int z = 0; z < ZZ; ++z) dp = fmaf(uz[z], us[z], dp);
        float e = __expf(dp * 0.25f);   // / sqrt(Z=16)
        unsafeAtomicAdd(&S[(j0 + jl) * BB + bg], e);
    }
}

// ---- Pass C: sacc[k][z][b] += u * ( exp(d)/S + bias ) ----
extern "C" __global__ __launch_bounds__(256)
void kC(const float* __restrict__ xT, const float* __restrict__ W,
        const float* __restrict__ bias, const float* __restrict__ usum,
        const float* __restrict__ S, float* __restrict__ sacc) {
    const int jcb = blockIdx.x * JCB;
    const int k   = blockIdx.y;
    const int bc  = blockIdx.z;
    const int t   = threadIdx.x;
    const int w   = __builtin_amdgcn_readfirstlane(t >> 6);
    const int lb  = t & 63;
    const int bg  = bc * BCB + lb;

    float us[ZZ];
#pragma unroll
    for (int z = 0; z < ZZ; ++z) us[z] = usum[(k * ZZ + z) * BB + bg];

    float sc[ZZ];
#pragma unroll
    for (int z = 0; z < ZZ; ++z) sc[z] = 0.f;

    const int j0 = jcb + w * JPW;
    const float* Wk = W + ((size_t)k * JJ + j0) * II * ZZ;
#pragma unroll
    for (int jl = 0; jl < JPW; ++jl) {
        const float4* xp = (const float4*)(xT + ((size_t)(j0 + jl) * BB + bg) * II);
        float4 xa = xp[0], xb4 = xp[1];
        float uz[ZZ];
        compute_uz(Wk + (size_t)jl * II * ZZ, xa, xb4, uz);
        float dp = 0.f;
#pragma unroll
        for (int z = 0; z < ZZ; ++z) dp = fmaf(uz[z], us[z], dp);
        float e  = __expf(dp * 0.25f);
        float Sv = S[(j0 + jl) * BB + bg];               // coalesced
        float bj = bias[k * JJ + j0 + jl];               // uniform -> s_load
        float ci = fmaf(e, __builtin_amdgcn_rcpf(Sv), bj);
#pragma unroll
        for (int z = 0; z < ZZ; ++z) sc[z] = fmaf(uz[z], ci, sc[z]);
    }
#pragma unroll
    for (int z = 0; z < ZZ; ++z)
        unsafeAtomicAdd(&sacc[(k * ZZ + z) * BB + bg], sc[z]);
}

// ---- Pass D: squash, sacc[k][z][b] -> out[b][k][z] ----
extern "C" __global__ __launch_bounds__(256)
void kD(const float* __restrict__ sacc, float* __restrict__ out) {
    int p = blockIdx.x * blockDim.x + threadIdx.x;
    if (p >= KK * BB) return;
    int k = p >> 7;       // /128
    int b = p & 127;
    float v[ZZ];
    float nsq = 0.f;
#pragma unroll
    for (int z = 0; z < ZZ; ++z) {
        v[z] = sacc[(k * ZZ + z) * BB + b];   // coalesced per z
        nsq  = fmaf(v[z], v[z], nsq);
    }
    float n = sqrtf(nsq);
    float scale = (1.f - 1.f / (__expf(n) + 1e-20f)) / (n + 1e-20f);
#pragma unroll
    for (int z = 0; z < ZZ; ++z)
        out[((size_t)b * KK + k) * ZZ + z] = v[z] * scale;
}

extern "C" void kernel_launch(void* const* d_in, const int* in_sizes, int n_in,
                              void* d_out, int out_size, void* d_ws, size_t ws_size,
                              hipStream_t stream) {
    const float* x    = (const float*)d_in[0];
    const float* W    = (const float*)d_in[1];
    const float* bias = (const float*)d_in[2];
    float*       out  = (float*)d_out;

    float* ws    = (float*)d_ws;
    float* usum  = ws;                       // [K][Z][B]
    float* S     = ws + N_USUM;              // [J][B]
    float* saccp = ws + N_USUM + N_S;        // [K][Z][B]
    float* xT    = ws + N_ACC;               // [J][B][I]

    hipMemsetAsync(d_ws, 0, (size_t)N_ACC * sizeof(float), stream);

    kT<<<(N_XT / 4) / 256, 256, 0, stream>>>(x, xT);

    dim3 grid(NJC, KK, NBC);
    kA<<<grid, 256, 0, stream>>>(xT, W, usum);
    kB<<<grid, 256, 0, stream>>>(xT, W, usum, S);
    kC<<<grid, 256, 0, stream>>>(xT, W, bias, usum, S, saccp);
    kD<<<(KK * BB + 255) / 256, 256, 0, stream>>>(saccp, out);
}

// Round 4
// 187.882 us; speedup vs baseline: 1.2291x; 1.2291x over previous
//
#include <hip/hip_runtime.h>
#include <math.h>

// Problem constants
#define BB 128
#define KK 32
#define JJ 1152
#define II 8
#define ZZ 16

#define JCB 32              // j's per block (hot kernels)
#define NJC (JJ / JCB)      // 36 chunks
#define JPW (JCB / 4)       // 8 j's per wave (4 waves/block)
#define BCB 64              // b's per block (one per lane)
#define NBC (BB / BCB)      // 2

#define WS_FLOATS (JCB * II * ZZ)   // 4096 floats = 16 KB LDS per block

// Workspace layout (floats): accumulators first (memset), xT after.
#define N_USUM (KK * ZZ * BB)   // [k][z][b]   65536
#define N_S    (JJ * BB)        // [j][b]     147456
#define N_SACC (KK * ZZ * BB)   // [k][z][b]   65536
#define N_ACC  (N_USUM + N_S + N_SACC)
#define N_XT   (JJ * BB * II)   // [j][b][i] 1179648

// ---- Transpose: x[b][j][i] -> xT[j][b][i] (float4 granularity) ----
extern "C" __global__ __launch_bounds__(256)
void kT(const float* __restrict__ x, float* __restrict__ xT) {
    int idx = blockIdx.x * 256 + threadIdx.x;       // float4 index in xT
    int j  = idx >> 8;            // / (BB*2)
    int r  = idx & 255;
    int b  = r >> 1;
    int i4 = r & 1;
    float4 v = ((const float4*)x)[((size_t)b * JJ + j) * 2 + i4];
    ((float4*)xT)[idx] = v;       // fully coalesced write
}

// Stage this block's W slice (32 j x 8 i x 16 z = 16 KB) into LDS, coalesced.
__device__ __forceinline__ void stage_W(const float* __restrict__ W,
                                        float* Ws, int k, int jcb) {
    const float4* Wg = (const float4*)(W + ((size_t)k * JJ + jcb) * II * ZZ);
    float4* Wl = (float4*)Ws;
#pragma unroll
    for (int it = 0; it < 4; ++it) {
        int f4 = it * 256 + threadIdx.x;   // 0..1023
        Wl[f4] = Wg[f4];
    }
}

// Compute u[z] for one (b, j): W via LDS broadcast reads, x in regs.
__device__ __forceinline__ void compute_uz(const float* Wj,
                                           const float xi[II], float uz[ZZ]) {
#pragma unroll
    for (int z = 0; z < ZZ; ++z) uz[z] = 0.f;
#pragma unroll
    for (int i = 0; i < II; ++i) {
        const float4* wp = (const float4*)(Wj + i * ZZ);   // ds_read_b128 broadcast
        float4 w0 = wp[0], w1 = wp[1], w2 = wp[2], w3 = wp[3];
        float xv = xi[i];
        uz[0]  = fmaf(xv, w0.x, uz[0]);  uz[1]  = fmaf(xv, w0.y, uz[1]);
        uz[2]  = fmaf(xv, w0.z, uz[2]);  uz[3]  = fmaf(xv, w0.w, uz[3]);
        uz[4]  = fmaf(xv, w1.x, uz[4]);  uz[5]  = fmaf(xv, w1.y, uz[5]);
        uz[6]  = fmaf(xv, w1.z, uz[6]);  uz[7]  = fmaf(xv, w1.w, uz[7]);
        uz[8]  = fmaf(xv, w2.x, uz[8]);  uz[9]  = fmaf(xv, w2.y, uz[9]);
        uz[10] = fmaf(xv, w2.z, uz[10]); uz[11] = fmaf(xv, w2.w, uz[11]);
        uz[12] = fmaf(xv, w3.x, uz[12]); uz[13] = fmaf(xv, w3.y, uz[13]);
        uz[14] = fmaf(xv, w3.z, uz[14]); uz[15] = fmaf(xv, w3.w, uz[15]);
    }
}

// ---- Pass A: usum[k][z][b] = sum_j u[b,k,j,z] ----
extern "C" __global__ __launch_bounds__(256)
void kA(const float* __restrict__ xT, const float* __restrict__ W,
        float* __restrict__ usum) {
    __shared__ float Ws[WS_FLOATS];
    const int jcb = blockIdx.x * JCB;
    const int k   = blockIdx.y;
    const int bc  = blockIdx.z;
    stage_W(W, Ws, k, jcb);
    __syncthreads();

    const int t  = threadIdx.x;
    const int w  = t >> 6;
    const int lb = t & 63;
    const int bg = bc * BCB + lb;

    float acc[ZZ];
#pragma unroll
    for (int z = 0; z < ZZ; ++z) acc[z] = 0.f;

    const int j0 = jcb + w * JPW;
#pragma unroll
    for (int jl = 0; jl < JPW; ++jl) {
        const float4* xp = (const float4*)(xT + ((size_t)(j0 + jl) * BB + bg) * II);
        float4 xa = xp[0], xb4 = xp[1];          // coalesced 32B/lane
        const float xi[II] = {xa.x, xa.y, xa.z, xa.w, xb4.x, xb4.y, xb4.z, xb4.w};
        float uz[ZZ];
        compute_uz(Ws + (w * JPW + jl) * II * ZZ, xi, uz);
#pragma unroll
        for (int z = 0; z < ZZ; ++z) acc[z] += uz[z];
    }
#pragma unroll
    for (int z = 0; z < ZZ; ++z)
        unsafeAtomicAdd(&usum[(k * ZZ + z) * BB + bg], acc[z]);
}

// ---- Pass B: S[j][b] = sum_k exp( dot_z(u, usum) / 4 ) ----
// Register-light form: dp = sum_i x_i * ( sum_z W[i][z]*us[z] )
extern "C" __global__ __launch_bounds__(256)
void kB(const float* __restrict__ xT, const float* __restrict__ W,
        const float* __restrict__ usum, float* __restrict__ S) {
    __shared__ float Ws[WS_FLOATS];
    const int jcb = blockIdx.x * JCB;
    const int k   = blockIdx.y;
    const int bc  = blockIdx.z;
    stage_W(W, Ws, k, jcb);
    __syncthreads();

    const int t  = threadIdx.x;
    const int w  = t >> 6;
    const int lb = t & 63;
    const int bg = bc * BCB + lb;

    float us[ZZ];
#pragma unroll
    for (int z = 0; z < ZZ; ++z) us[z] = usum[(k * ZZ + z) * BB + bg];

    const int j0 = jcb + w * JPW;
#pragma unroll
    for (int jl = 0; jl < JPW; ++jl) {
        const float4* xp = (const float4*)(xT + ((size_t)(j0 + jl) * BB + bg) * II);
        float4 xa = xp[0], xb4 = xp[1];
        const float xi[II] = {xa.x, xa.y, xa.z, xa.w, xb4.x, xb4.y, xb4.z, xb4.w};
        const float* Wj = Ws + (w * JPW + jl) * II * ZZ;
        float dp = 0.f;
#pragma unroll
        for (int i = 0; i < II; ++i) {
            const float4* wp = (const float4*)(Wj + i * ZZ);
            float4 w0 = wp[0], w1 = wp[1], w2 = wp[2], w3 = wp[3];
            float tacc = w0.x * us[0];
            tacc = fmaf(w0.y, us[1],  tacc); tacc = fmaf(w0.z, us[2],  tacc);
            tacc = fmaf(w0.w, us[3],  tacc); tacc = fmaf(w1.x, us[4],  tacc);
            tacc = fmaf(w1.y, us[5],  tacc); tacc = fmaf(w1.z, us[6],  tacc);
            tacc = fmaf(w1.w, us[7],  tacc); tacc = fmaf(w2.x, us[8],  tacc);
            tacc = fmaf(w2.y, us[9],  tacc); tacc = fmaf(w2.z, us[10], tacc);
            tacc = fmaf(w2.w, us[11], tacc); tacc = fmaf(w3.x, us[12], tacc);
            tacc = fmaf(w3.y, us[13], tacc); tacc = fmaf(w3.z, us[14], tacc);
            tacc = fmaf(w3.w, us[15], tacc);
            dp = fmaf(xi[i], tacc, dp);
        }
        float e = __expf(dp * 0.25f);   // / sqrt(Z=16)
        unsafeAtomicAdd(&S[(j0 + jl) * BB + bg], e);
    }
}

// ---- Pass C: sacc[k][z][b] += u * ( exp(d)/S + bias ) ----
extern "C" __global__ __launch_bounds__(256)
void kC(const float* __restrict__ xT, const float* __restrict__ W,
        const float* __restrict__ bias, const float* __restrict__ usum,
        const float* __restrict__ S, float* __restrict__ sacc) {
    __shared__ float Ws[WS_FLOATS];
    const int jcb = blockIdx.x * JCB;
    const int k   = blockIdx.y;
    const int bc  = blockIdx.z;
    stage_W(W, Ws, k, jcb);
    __syncthreads();

    const int t  = threadIdx.x;
    const int w  = t >> 6;
    const int lb = t & 63;
    const int bg = bc * BCB + lb;

    float us[ZZ];
#pragma unroll
    for (int z = 0; z < ZZ; ++z) us[z] = usum[(k * ZZ + z) * BB + bg];

    float sc[ZZ];
#pragma unroll
    for (int z = 0; z < ZZ; ++z) sc[z] = 0.f;

    const int j0 = jcb + w * JPW;
#pragma unroll
    for (int jl = 0; jl < JPW; ++jl) {
        const float4* xp = (const float4*)(xT + ((size_t)(j0 + jl) * BB + bg) * II);
        float4 xa = xp[0], xb4 = xp[1];
        const float xi[II] = {xa.x, xa.y, xa.z, xa.w, xb4.x, xb4.y, xb4.z, xb4.w};
        float uz[ZZ];
        compute_uz(Ws + (w * JPW + jl) * II * ZZ, xi, uz);
        float dp = 0.f;
#pragma unroll
        for (int z = 0; z < ZZ; ++z) dp = fmaf(uz[z], us[z], dp);
        float e  = __expf(dp * 0.25f);
        float Sv = S[(j0 + jl) * BB + bg];               // coalesced
        float bj = bias[k * JJ + j0 + jl];               // uniform -> s_load (tiny)
        float ci = fmaf(e, __builtin_amdgcn_rcpf(Sv), bj);
#pragma unroll
        for (int z = 0; z < ZZ; ++z) sc[z] = fmaf(uz[z], ci, sc[z]);
    }
#pragma unroll
    for (int z = 0; z < ZZ; ++z)
        unsafeAtomicAdd(&sacc[(k * ZZ + z) * BB + bg], sc[z]);
}

// ---- Pass D: squash, sacc[k][z][b] -> out[b][k][z] ----
extern "C" __global__ __launch_bounds__(256)
void kD(const float* __restrict__ sacc, float* __restrict__ out) {
    int p = blockIdx.x * blockDim.x + threadIdx.x;
    if (p >= KK * BB) return;
    int k = p >> 7;       // /128
    int b = p & 127;
    float v[ZZ];
    float nsq = 0.f;
#pragma unroll
    for (int z = 0; z < ZZ; ++z) {
        v[z] = sacc[(k * ZZ + z) * BB + b];   // coalesced per z
        nsq  = fmaf(v[z], v[z], nsq);
    }
    float n = sqrtf(nsq);
    float scale = (1.f - 1.f / (__expf(n) + 1e-20f)) / (n + 1e-20f);
#pragma unroll
    for (int z = 0; z < ZZ; ++z)
        out[((size_t)b * KK + k) * ZZ + z] = v[z] * scale;
}

extern "C" void kernel_launch(void* const* d_in, const int* in_sizes, int n_in,
                              void* d_out, int out_size, void* d_ws, size_t ws_size,
                              hipStream_t stream) {
    const float* x    = (const float*)d_in[0];
    const float* W    = (const float*)d_in[1];
    const float* bias = (const float*)d_in[2];
    float*       out  = (float*)d_out;

    float* ws    = (float*)d_ws;
    float* usum  = ws;                       // [K][Z][B]
    float* S     = ws + N_USUM;              // [J][B]
    float* saccp = ws + N_USUM + N_S;        // [K][Z][B]
    float* xT    = ws + N_ACC;               // [J][B][I]

    hipMemsetAsync(d_ws, 0, (size_t)N_ACC * sizeof(float), stream);

    kT<<<(N_XT / 4) / 256, 256, 0, stream>>>(x, xT);

    dim3 grid(NJC, KK, NBC);
    kA<<<grid, 256, 0, stream>>>(xT, W, usum);
    kB<<<grid, 256, 0, stream>>>(xT, W, usum, S);
    kC<<<grid, 256, 0, stream>>>(xT, W, bias, usum, S, saccp);
    kD<<<(KK * BB + 255) / 256, 256, 0, stream>>>(saccp, out);
}

// Round 5
// 186.109 us; speedup vs baseline: 1.2409x; 1.0095x over previous
//
#include <hip/hip_runtime.h>
#include <math.h>

// Problem constants
#define BB 128
#define KK 32
#define JJ 1152
#define II 8
#define ZZ 16

#define JCB 32              // j's per block (hot kernels)
#define NJC (JJ / JCB)      // 36 chunks
#define JPW (JCB / 4)       // 8 j's per wave (4 waves/block)
#define BCB 64              // b's per block (one per lane)
#define NBC (BB / BCB)      // 2

#define WS_FLOATS (JCB * II * ZZ)   // 4096 floats = 16 KB LDS per block

// Workspace layout (floats): accumulators first (memset), xT after.
#define N_USUM (KK * ZZ * BB)   // [k][z][b]   65536
#define N_S    (JJ * BB)        // [j][b]     147456
#define N_SACC (KK * ZZ * BB)   // [k][z][b]   65536
#define N_ACC  (N_USUM + N_S + N_SACC)
#define N_XT   (JJ * BB * II)   // [j][b][i] 1179648

// ---- Transpose: x[b][j][i] -> xT[j][b][i] (float4 granularity) ----
extern "C" __global__ __launch_bounds__(256)
void kT(const float* __restrict__ x, float* __restrict__ xT) {
    int idx = blockIdx.x * 256 + threadIdx.x;       // float4 index in xT
    int j  = idx >> 8;            // / (BB*2)
    int r  = idx & 255;
    int b  = r >> 1;
    int i4 = r & 1;
    float4 v = ((const float4*)x)[((size_t)b * JJ + j) * 2 + i4];
    ((float4*)xT)[idx] = v;       // fully coalesced write
}

// Stage this block's W slice (32 j x 8 i x 16 z = 16 KB) into LDS, coalesced.
__device__ __forceinline__ void stage_W(const float* __restrict__ W,
                                        float* Ws, int k, int jcb) {
    const float4* Wg = (const float4*)(W + ((size_t)k * JJ + jcb) * II * ZZ);
    float4* Wl = (float4*)Ws;
#pragma unroll
    for (int it = 0; it < 4; ++it) {
        int f4 = it * 256 + threadIdx.x;   // 0..1023
        Wl[f4] = Wg[f4];
    }
}

// Compute u[z] for one (b, j): W via LDS broadcast reads, x in regs.
__device__ __forceinline__ void compute_uz(const float* Wj,
                                           const float xi[II], float uz[ZZ]) {
#pragma unroll
    for (int z = 0; z < ZZ; ++z) uz[z] = 0.f;
#pragma unroll
    for (int i = 0; i < II; ++i) {
        const float4* wp = (const float4*)(Wj + i * ZZ);   // ds_read_b128 broadcast
        float4 w0 = wp[0], w1 = wp[1], w2 = wp[2], w3 = wp[3];
        float xv = xi[i];
        uz[0]  = fmaf(xv, w0.x, uz[0]);  uz[1]  = fmaf(xv, w0.y, uz[1]);
        uz[2]  = fmaf(xv, w0.z, uz[2]);  uz[3]  = fmaf(xv, w0.w, uz[3]);
        uz[4]  = fmaf(xv, w1.x, uz[4]);  uz[5]  = fmaf(xv, w1.y, uz[5]);
        uz[6]  = fmaf(xv, w1.z, uz[6]);  uz[7]  = fmaf(xv, w1.w, uz[7]);
        uz[8]  = fmaf(xv, w2.x, uz[8]);  uz[9]  = fmaf(xv, w2.y, uz[9]);
        uz[10] = fmaf(xv, w2.z, uz[10]); uz[11] = fmaf(xv, w2.w, uz[11]);
        uz[12] = fmaf(xv, w3.x, uz[12]); uz[13] = fmaf(xv, w3.y, uz[13]);
        uz[14] = fmaf(xv, w3.z, uz[14]); uz[15] = fmaf(xv, w3.w, uz[15]);
    }
}

// ---- Pass A: usum[k][z][b] = sum_j u[b,k,j,z] ----
extern "C" __global__ __launch_bounds__(256)
void kA(const float* __restrict__ xT, const float* __restrict__ W,
        float* __restrict__ usum) {
    __shared__ float Ws[WS_FLOATS];
    const int jcb = blockIdx.x * JCB;
    const int k   = blockIdx.y;
    const int bc  = blockIdx.z;
    stage_W(W, Ws, k, jcb);
    __syncthreads();

    const int t  = threadIdx.x;
    const int w  = t >> 6;
    const int lb = t & 63;
    const int bg = bc * BCB + lb;

    float acc[ZZ];
#pragma unroll
    for (int z = 0; z < ZZ; ++z) acc[z] = 0.f;

    const int j0 = jcb + w * JPW;
#pragma unroll
    for (int jl = 0; jl < JPW; ++jl) {
        const float4* xp = (const float4*)(xT + ((size_t)(j0 + jl) * BB + bg) * II);
        float4 xa = xp[0], xb4 = xp[1];          // coalesced 32B/lane
        const float xi[II] = {xa.x, xa.y, xa.z, xa.w, xb4.x, xb4.y, xb4.z, xb4.w};
        float uz[ZZ];
        compute_uz(Ws + (w * JPW + jl) * II * ZZ, xi, uz);
#pragma unroll
        for (int z = 0; z < ZZ; ++z) acc[z] += uz[z];
    }
#pragma unroll
    for (int z = 0; z < ZZ; ++z)
        unsafeAtomicAdd(&usum[(k * ZZ + z) * BB + bg], acc[z]);
}

// ---- Pass B: S[j][b] = sum_k exp( dot_z(u, usum) / 4 ) ----
// Register-light form: dp = sum_i x_i * ( sum_z W[i][z]*us[z] )
extern "C" __global__ __launch_bounds__(256)
void kB(const float* __restrict__ xT, const float* __restrict__ W,
        const float* __restrict__ usum, float* __restrict__ S) {
    __shared__ float Ws[WS_FLOATS];
    const int jcb = blockIdx.x * JCB;
    const int k   = blockIdx.y;
    const int bc  = blockIdx.z;
    stage_W(W, Ws, k, jcb);
    __syncthreads();

    const int t  = threadIdx.x;
    const int w  = t >> 6;
    const int lb = t & 63;
    const int bg = bc * BCB + lb;

    float us[ZZ];
#pragma unroll
    for (int z = 0; z < ZZ; ++z) us[z] = usum[(k * ZZ + z) * BB + bg];

    const int j0 = jcb + w * JPW;
#pragma unroll
    for (int jl = 0; jl < JPW; ++jl) {
        const float4* xp = (const float4*)(xT + ((size_t)(j0 + jl) * BB + bg) * II);
        float4 xa = xp[0], xb4 = xp[1];
        const float xi[II] = {xa.x, xa.y, xa.z, xa.w, xb4.x, xb4.y, xb4.z, xb4.w};
        const float* Wj = Ws + (w * JPW + jl) * II * ZZ;
        float dp = 0.f;
#pragma unroll
        for (int i = 0; i < II; ++i) {
            const float4* wp = (const float4*)(Wj + i * ZZ);
            float4 w0 = wp[0], w1 = wp[1], w2 = wp[2], w3 = wp[3];
            float tacc = w0.x * us[0];
            tacc = fmaf(w0.y, us[1],  tacc); tacc = fmaf(w0.z, us[2],  tacc);
            tacc = fmaf(w0.w, us[3],  tacc); tacc = fmaf(w1.x, us[4],  tacc);
            tacc = fmaf(w1.y, us[5],  tacc); tacc = fmaf(w1.z, us[6],  tacc);
            tacc = fmaf(w1.w, us[7],  tacc); tacc = fmaf(w2.x, us[8],  tacc);
            tacc = fmaf(w2.y, us[9],  tacc); tacc = fmaf(w2.z, us[10], tacc);
            tacc = fmaf(w2.w, us[11], tacc); tacc = fmaf(w3.x, us[12], tacc);
            tacc = fmaf(w3.y, us[13], tacc); tacc = fmaf(w3.z, us[14], tacc);
            tacc = fmaf(w3.w, us[15], tacc);
            dp = fmaf(xi[i], tacc, dp);
        }
        float e = __expf(dp * 0.25f);   // / sqrt(Z=16)
        unsafeAtomicAdd(&S[(j0 + jl) * BB + bg], e);
    }
}

// ---- Pass C: sacc[k][z][b] += u * ( exp(d)/S + bias ) ----
extern "C" __global__ __launch_bounds__(256)
void kC(const float* __restrict__ xT, const float* __restrict__ W,
        const float* __restrict__ bias, const float* __restrict__ usum,
        const float* __restrict__ S, float* __restrict__ sacc) {
    __shared__ float Ws[WS_FLOATS];
    const int jcb = blockIdx.x * JCB;
    const int k   = blockIdx.y;
    const int bc  = blockIdx.z;
    stage_W(W, Ws, k, jcb);
    __syncthreads();

    const int t  = threadIdx.x;
    const int w  = t >> 6;
    const int lb = t & 63;
    const int bg = bc * BCB + lb;

    float us[ZZ];
#pragma unroll
    for (int z = 0; z < ZZ; ++z) us[z] = usum[(k * ZZ + z) * BB + bg];

    float sc[ZZ];
#pragma unroll
    for (int z = 0; z < ZZ; ++z) sc[z] = 0.f;

    const int j0 = jcb + w * JPW;
#pragma unroll
    for (int jl = 0; jl < JPW; ++jl) {
        const float4* xp = (const float4*)(xT + ((size_t)(j0 + jl) * BB + bg) * II);
        float4 xa = xp[0], xb4 = xp[1];
        const float xi[II] = {xa.x, xa.y, xa.z, xa.w, xb4.x, xb4.y, xb4.z, xb4.w};
        float uz[ZZ];
        compute_uz(Ws + (w * JPW + jl) * II * ZZ, xi, uz);
        float dp = 0.f;
#pragma unroll
        for (int z = 0; z < ZZ; ++z) dp = fmaf(uz[z], us[z], dp);
        float e  = __expf(dp * 0.25f);
        float Sv = S[(j0 + jl) * BB + bg];               // coalesced
        float bj = bias[k * JJ + j0 + jl];               // uniform -> s_load (tiny)
        float ci = fmaf(e, __builtin_amdgcn_rcpf(Sv), bj);
#pragma unroll
        for (int z = 0; z < ZZ; ++z) sc[z] = fmaf(uz[z], ci, sc[z]);
    }
#pragma unroll
    for (int z = 0; z < ZZ; ++z)
        unsafeAtomicAdd(&sacc[(k * ZZ + z) * BB + bg], sc[z]);
}

// ---- Pass D: squash, sacc[k][z][b] -> out[b][k][z] ----
extern "C" __global__ __launch_bounds__(256)
void kD(const float* __restrict__ sacc, float* __restrict__ out) {
    int p = blockIdx.x * blockDim.x + threadIdx.x;
    if (p >= KK * BB) return;
    int k = p >> 7;       // /128
    int b = p & 127;
    float v[ZZ];
    float nsq = 0.f;
#pragma unroll
    for (int z = 0; z < ZZ; ++z) {
        v[z] = sacc[(k * ZZ + z) * BB + b];   // coalesced per z
        nsq  = fmaf(v[z], v[z], nsq);
    }
    float n = sqrtf(nsq);
    float scale = (1.f - 1.f / (__expf(n) + 1e-20f)) / (n + 1e-20f);
#pragma unroll
    for (int z = 0; z < ZZ; ++z)
        out[((size_t)b * KK + k) * ZZ + z] = v[z] * scale;
}

extern "C" void kernel_launch(void* const* d_in, const int* in_sizes, int n_in,
                              void* d_out, int out_size, void* d_ws, size_t ws_size,
                              hipStream_t stream) {
    const float* x    = (const float*)d_in[0];
    const float* W    = (const float*)d_in[1];
    const float* bias = (const float*)d_in[2];
    float*       out  = (float*)d_out;

    float* ws    = (float*)d_ws;
    float* usum  = ws;                       // [K][Z][B]
    float* S     = ws + N_USUM;              // [J][B]
    float* saccp = ws + N_USUM + N_S;        // [K][Z][B]
    float* xT    = ws + N_ACC;               // [J][B][I]

    hipMemsetAsync(d_ws, 0, (size_t)N_ACC * sizeof(float), stream);

    kT<<<(N_XT / 4) / 256, 256, 0, stream>>>(x, xT);

    dim3 grid(NJC, KK, NBC);
    kA<<<grid, 256, 0, stream>>>(xT, W, usum);
    kB<<<grid, 256, 0, stream>>>(xT, W, usum, S);
    kC<<<grid, 256, 0, stream>>>(xT, W, bias, usum, S, saccp);
    kD<<<(KK * BB + 255) / 256, 256, 0, stream>>>(saccp, out);
}